// Round 4
// baseline (230.606 us; speedup 1.0000x reference)
//
#include <hip/hip_runtime.h>

#define BH_ 16
#define S_ 2048
#define D_ 128
#define QB_ 64
#define KB_ 64

typedef __attribute__((ext_vector_type(4))) float f32x4;
typedef __attribute__((ext_vector_type(8))) short bf16x8;
typedef unsigned short ushort_t;

__device__ __forceinline__ unsigned short f2bf(float x) {
  union { float f; unsigned int u; } v; v.f = x;
  unsigned int r = v.u + 0x7fffu + ((v.u >> 16) & 1u);  // RNE
  return (unsigned short)(r >> 16);
}
__device__ __forceinline__ float bf2f(unsigned short b) {
  union { float f; unsigned int u; } v; v.u = ((unsigned int)b) << 16;
  return v.f;
}
__device__ __forceinline__ void gload16(const void* g, void* l) {
  __builtin_amdgcn_global_load_lds(
      (const __attribute__((address_space(1))) unsigned int*)g,
      (__attribute__((address_space(3))) unsigned int*)l, 16, 0, 0);
}

// ---------- k0a: K (f32) -> Khi/Klo bf16, same [bh][s][d] layout ----------
__global__ __launch_bounds__(256) void convK(const float* __restrict__ K,
                                             ushort_t* __restrict__ hi,
                                             ushort_t* __restrict__ lo) {
  size_t i = (size_t)blockIdx.x * 256 + threadIdx.x;  // 8 floats per thread
  const float4* p = (const float4*)K + i * 2;
  float4 a = p[0], b = p[1];
  float xs[8] = {a.x, a.y, a.z, a.w, b.x, b.y, b.z, b.w};
  union { ushort_t u[8]; uint4 v; } H, L;
#pragma unroll
  for (int j = 0; j < 8; ++j) {
    unsigned short h = f2bf(xs[j]);
    H.u[j] = h;
    L.u[j] = f2bf(xs[j] - bf2f(h));
  }
  ((uint4*)hi)[i] = H.v;
  ((uint4*)lo)[i] = L.v;
}

// ---------- k0b: V (f32 [bh][s][d]) -> Vt bf16 [bh][d][s] ----------
__global__ __launch_bounds__(256) void transV(const float* __restrict__ V,
                                              ushort_t* __restrict__ Vt) {
  __shared__ ushort_t tile[64][136];
  const int tid = threadIdx.x;
  const int bh = blockIdx.y;
  const int s0 = blockIdx.x * 64;
  const float* Vb = V + ((size_t)bh * S_ + s0) * D_;
#pragma unroll
  for (int it = 0; it < 8; ++it) {
    int idx = it * 256 + tid;           // float4 index within 64x128 tile
    int fl = idx * 4;
    int s = fl >> 7, d = fl & 127;
    float4 f = *(const float4*)(Vb + (size_t)s * D_ + d);
    tile[s][d + 0] = f2bf(f.x);
    tile[s][d + 1] = f2bf(f.y);
    tile[s][d + 2] = f2bf(f.z);
    tile[s][d + 3] = f2bf(f.w);
  }
  __syncthreads();
  const int d = tid >> 1, half = tid & 1;
  union { ushort_t u[32]; uint4 v[4]; } T;
#pragma unroll
  for (int i = 0; i < 32; ++i) T.u[i] = tile[half * 32 + i][d];
  ushort_t* dst = Vt + (size_t)bh * D_ * S_ + (size_t)d * S_ + s0 + half * 32;
#pragma unroll
  for (int i = 0; i < 4; ++i) ((uint4*)dst)[i] = T.v[i];
}

// ---------- k1: single-pass attention with fused in-block rescale ----------
// Block = (bh, one q-tile of 64 rows). Heavy tiles launch first (LPT).
// K single-buffered (restaged after mid-iter barrier), V double-buffered.
// LDS = 72.25 KB -> 2 blocks/CU (8 waves). attn written unnormalized, then
// rescaled in-place by the same block while the tile is L2/L3-hot.
__global__ __launch_bounds__(256) void sdpa_main(
    const float* __restrict__ Q, const ushort_t* __restrict__ Khi,
    const ushort_t* __restrict__ Klo, const ushort_t* __restrict__ Vt,
    float* __restrict__ out, float* __restrict__ attn) {
  __shared__ ushort_t khi[KB_ * D_];      // 16 KB, XOR-swizzled content
  __shared__ ushort_t klo[KB_ * D_];      // 16 KB
  __shared__ ushort_t vts[2][D_ * KB_];   // 2 x 16 KB
  __shared__ ushort_t pls[4][16 * KB_];   // per-wave P tile, 8 KB
  __shared__ float invs[64];

  const int tid  = threadIdx.x;
  const int w    = tid >> 6;
  const int lane = tid & 63;
  const int g    = lane >> 4;
  const int c    = lane & 15;

  const int bh = blockIdx.y;
  const int qb = 31 - (int)blockIdx.x;    // heavy blocks first
  const int q0 = qb * QB_;
  const int nj = qb + 1;                  // k-tiles

  const float* Qb = Q + (size_t)bh * S_ * D_;
  const char* KhiB = (const char*)Khi + (size_t)bh * S_ * D_ * 2;
  const char* KloB = (const char*)Klo + (size_t)bh * S_ * D_ * 2;
  const char* VtB  = (const char*)Vt  + (size_t)bh * D_ * S_ * 2;
  float* outb  = out  + (size_t)bh * S_ * D_;
  float* attnb = attn + (size_t)bh * S_ * S_;

  // ---- zero-fill fully masked columns [q0+64, S) ----
  {
    const int colstart = q0 + QB_;
    for (int r = 0; r < QB_; ++r) {
      float* rowp = attnb + (size_t)(q0 + r) * S_;
      for (int col = colstart + tid * 4; col < S_; col += 1024)
        *(float4*)(rowp + col) = make_float4(0.f, 0.f, 0.f, 0.f);
    }
  }

  // stage K tile kb -> khi/klo; V tile kb -> vts[bi]. LDS dest linear,
  // global source carries the inverse XOR swizzle.
  auto stageK = [&](int kb) {
    const char* hs = KhiB + (size_t)kb * (KB_ * D_ * 2);
    const char* ls = KloB + (size_t)kb * (KB_ * D_ * 2);
#pragma unroll
    for (int i = 0; i < 4; ++i) {
      int ch = w * 4 + i;
      int db = ch * 1024 + lane * 16;
      int r = db >> 8, cb = db & 255;
      int so = r * 256 + (cb ^ ((r & 7) << 4));
      gload16(hs + so, (char*)khi + ch * 1024);
      gload16(ls + so, (char*)klo + ch * 1024);
    }
  };
  auto stageV = [&](int bi, int kb) {
    const char* vs = VtB + (size_t)kb * (KB_ * 2);
#pragma unroll
    for (int i = 0; i < 4; ++i) {
      int ch = w * 4 + i;
      int db = ch * 1024 + lane * 16;
      int r = db >> 7, cb = db & 127;
      int so = r * (S_ * 2) + (cb ^ ((r & 7) << 4));
      gload16(vs + so, (char*)vts[bi] + ch * 1024);
    }
  };

  // ---- Q fragments (bf16 hi/lo) ----
  bf16x8 qhi[4], qlo[4];
  {
    const float* qrow = Qb + (size_t)(q0 + w * 16 + c) * D_;
#pragma unroll
    for (int ch = 0; ch < 4; ++ch) {
      const float* src = qrow + ch * 32 + g * 8;
      float4 a = *(const float4*)src;
      float4 b = *(const float4*)(src + 4);
      float xs[8] = {a.x, a.y, a.z, a.w, b.x, b.y, b.z, b.w};
#pragma unroll
      for (int i = 0; i < 8; ++i) {
        unsigned short h = f2bf(xs[i]);
        qhi[ch][i] = (short)h;
        qlo[ch][i] = (short)f2bf(xs[i] - bf2f(h));
      }
    }
  }

  const f32x4 zero4 = {0.f, 0.f, 0.f, 0.f};
  f32x4 oacc[8];
  float rs[4] = {0.f, 0.f, 0.f, 0.f};
#pragma unroll
  for (int dt = 0; dt < 8; ++dt) oacc[dt] = zero4;

  stageK(0);
  stageV(0, 0);
  __syncthreads();  // vmcnt(0) drain: tile 0 staged

  for (int j = 0; j < nj; ++j) {
    // ---- QK^T (3-way hi/lo split) from khi/klo ----
    f32x4 acc[4];
#pragma unroll
    for (int t = 0; t < 4; ++t) acc[t] = zero4;
#pragma unroll
    for (int c2 = 0; c2 < 4; ++c2) {
      bf16x8 kh[4], kl[4];
#pragma unroll
      for (int t = 0; t < 4; ++t) {
        int row = t * 16 + c;
        int off = row * 256 + (((c2 * 64 + g * 16)) ^ ((row & 7) << 4));
        kh[t] = *(const bf16x8*)((const char*)khi + off);
        kl[t] = *(const bf16x8*)((const char*)klo + off);
      }
#pragma unroll
      for (int t = 0; t < 4; ++t)
        acc[t] = __builtin_amdgcn_mfma_f32_16x16x32_bf16(qhi[c2], kh[t], acc[t], 0, 0, 0);
#pragma unroll
      for (int t = 0; t < 4; ++t)
        acc[t] = __builtin_amdgcn_mfma_f32_16x16x32_bf16(qlo[c2], kh[t], acc[t], 0, 0, 0);
#pragma unroll
      for (int t = 0; t < 4; ++t)
        acc[t] = __builtin_amdgcn_mfma_f32_16x16x32_bf16(qhi[c2], kl[t], acc[t], 0, 0, 0);
    }

    __syncthreads();  // all waves done reading khi/klo -> safe to restage

    if (j + 1 < nj) {
      stageK(j + 1);                 // overwrite K buffer (covered by exp+PV)
      stageV((j + 1) & 1, j + 1);    // other V buffer
    }

    // ---- exp (unnormalized), attn store, rsum accum, P -> LDS ----
    const int kb = j;
#pragma unroll
    for (int r2 = 0; r2 < 4; ++r2) {
      int qrow = g * 4 + r2;
      int qg = q0 + w * 16 + qrow;
      float* arow = attnb + (size_t)qg * S_;
#pragma unroll
      for (int t = 0; t < 4; ++t) {
        int kc = t * 16 + c;
        int kg = kb * KB_ + kc;
        float e = (kg <= qg) ? __expf(acc[t][r2]) : 0.f;
        rs[r2] += e;
        arow[kg] = e;
        int off = qrow * 128 + ((kc * 2) ^ ((qrow & 7) << 4));
        *(ushort_t*)((char*)pls[w] + off) = f2bf(e);
      }
    }

    // ---- PV (own-wave pls: lgkmcnt-ordered; vts[j&1] stable) ----
    bf16x8 pa[2];
#pragma unroll
    for (int ks = 0; ks < 2; ++ks) {
      int off = c * 128 + ((ks * 64 + g * 16) ^ ((c & 7) << 4));
      pa[ks] = *(const bf16x8*)((const char*)pls[w] + off);
    }
#pragma unroll
    for (int ks = 0; ks < 2; ++ks) {
#pragma unroll
      for (int dt = 0; dt < 8; ++dt) {
        int d = dt * 16 + c;
        int off = d * 128 + ((ks * 64 + g * 16) ^ ((d & 7) << 4));
        bf16x8 vf = *(const bf16x8*)((const char*)vts[j & 1] + off);
        oacc[dt] = __builtin_amdgcn_mfma_f32_16x16x32_bf16(pa[ks], vf, oacc[dt], 0, 0, 0);
      }
    }

    __syncthreads();  // vmcnt(0): next K/V staged; attn stores drained
  }

  // ---- epilogue: row sums -> invs; out = O * inv * q ----
  float inv[4];
#pragma unroll
  for (int r2 = 0; r2 < 4; ++r2) {
    float s0 = rs[r2];
#pragma unroll
    for (int m = 1; m <= 8; m <<= 1) s0 += __shfl_xor(s0, m, 64);
    inv[r2] = 1.0f / s0;
    if (c == 0) invs[w * 16 + g * 4 + r2] = inv[r2];
  }
#pragma unroll
  for (int dt = 0; dt < 8; ++dt) {
#pragma unroll
    for (int r2 = 0; r2 < 4; ++r2) {
      int qg = q0 + w * 16 + g * 4 + r2;
      int d = dt * 16 + c;
      outb[(size_t)qg * D_ + d] = oacc[dt][r2] * inv[r2] * Qb[(size_t)qg * D_ + d];
    }
  }
  __syncthreads();  // invs visible; attn stores from last iter visible (L2)

  // ---- fused rescale: attn rows *= inv, cols [0, q0+64) (L2/L3-hot) ----
  // In-tile upper-triangle entries were stored as 0.0 -> no boundary logic.
  const int W = q0 + QB_;
  for (int r = w; r < QB_; r += 4) {
    const float iv = invs[r];
    float* row = attnb + (size_t)(q0 + r) * S_;
    for (int col = lane * 4; col < W; col += 256) {
      float4 x = *(const float4*)(row + col);
      x.x *= iv; x.y *= iv; x.z *= iv; x.w *= iv;
      *(float4*)(row + col) = x;
    }
  }
}

// ---------- fallback (round-1 kernel, self-contained) ----------
__global__ __launch_bounds__(256, 2)
void sdpa_fallback(const float* __restrict__ Q, const float* __restrict__ K,
                   const float* __restrict__ V, float* __restrict__ out,
                   float* __restrict__ attn)
{
  __shared__ unsigned short khi[KB_ * D_];
  __shared__ unsigned short klo[KB_ * D_];
  __shared__ unsigned short vts[D_ * KB_];
  __shared__ unsigned short pls[4][16 * KB_];

  const int tid  = threadIdx.x;
  const int w    = tid >> 6;
  const int lane = tid & 63;
  const int g    = lane >> 4;
  const int c    = lane & 15;

  const int bh = blockIdx.y;
  const int qb = (int)gridDim.x - 1 - (int)blockIdx.x;
  const int q0 = qb * QB_;

  const float* Qb = Q + (size_t)bh * S_ * D_;
  const float* Kb = K + (size_t)bh * S_ * D_;
  const float* Vb = V + (size_t)bh * S_ * D_;
  float* outb  = out  + (size_t)bh * S_ * D_;
  float* attnb = attn + (size_t)bh * S_ * S_;

  {
    const int colstart = q0 + QB_;
    for (int r = 0; r < QB_; ++r) {
      float* rowp = attnb + (size_t)(q0 + r) * S_;
      for (int col = colstart + tid * 4; col < S_; col += 1024)
        *(float4*)(rowp + col) = make_float4(0.f, 0.f, 0.f, 0.f);
    }
  }

  bf16x8 qhi[4], qlo[4];
  {
    const float* qrow = Qb + (size_t)(q0 + w * 16 + c) * D_;
#pragma unroll
    for (int ch = 0; ch < 4; ++ch) {
      const float* src = qrow + ch * 32 + g * 8;
      float4 a = *(const float4*)src;
      float4 b = *(const float4*)(src + 4);
      float xs[8] = {a.x, a.y, a.z, a.w, b.x, b.y, b.z, b.w};
#pragma unroll
      for (int i = 0; i < 8; ++i) {
        unsigned short h = f2bf(xs[i]);
        unsigned short l = f2bf(xs[i] - bf2f(h));
        qhi[ch][i] = (short)h;
        qlo[ch][i] = (short)l;
      }
    }
  }

  auto stageK = [&](int kb) {
#pragma unroll
    for (int rr = 0; rr < 8; ++rr) {
      int flat = tid * 4 + rr * 1024;
      int kj = flat >> 7, d0 = flat & 127;
      const float* src = Kb + (size_t)(kb * KB_ + kj) * D_ + d0;
      float4 f = *(const float4*)src;
      unsigned short h0 = f2bf(f.x), h1 = f2bf(f.y), h2 = f2bf(f.z), h3 = f2bf(f.w);
      unsigned short l0 = f2bf(f.x - bf2f(h0)), l1 = f2bf(f.y - bf2f(h1));
      unsigned short l2 = f2bf(f.z - bf2f(h2)), l3 = f2bf(f.w - bf2f(h3));
      int off = kj * 256 + ((d0 * 2) ^ ((kj & 7) << 4));
      *(uint2*)((char*)khi + off) =
          make_uint2((unsigned)h0 | ((unsigned)h1 << 16), (unsigned)h2 | ((unsigned)h3 << 16));
      *(uint2*)((char*)klo + off) =
          make_uint2((unsigned)l0 | ((unsigned)l1 << 16), (unsigned)l2 | ((unsigned)l3 << 16));
    }
  };

  const f32x4 zero4 = {0.f, 0.f, 0.f, 0.f};
  auto computeS = [&](f32x4* acc) {
#pragma unroll
    for (int t = 0; t < 4; ++t) {
      acc[t] = zero4;
      int row = t * 16 + c;
      int rbase = row * 256;
      int sw = (row & 7) << 4;
#pragma unroll
      for (int c2 = 0; c2 < 4; ++c2) {
        int off = rbase + ((c2 * 64 + g * 16) ^ sw);
        bf16x8 kh_ = *(const bf16x8*)((const char*)khi + off);
        bf16x8 kl_ = *(const bf16x8*)((const char*)klo + off);
        acc[t] = __builtin_amdgcn_mfma_f32_16x16x32_bf16(qhi[c2], kh_, acc[t], 0, 0, 0);
        acc[t] = __builtin_amdgcn_mfma_f32_16x16x32_bf16(qhi[c2], kl_, acc[t], 0, 0, 0);
        acc[t] = __builtin_amdgcn_mfma_f32_16x16x32_bf16(qlo[c2], kh_, acc[t], 0, 0, 0);
      }
    }
  };

  float rsum[4] = {0.f, 0.f, 0.f, 0.f};
  for (int kb = 0; kb <= qb; ++kb) {
    __syncthreads();
    stageK(kb);
    __syncthreads();
    f32x4 acc[4];
    computeS(acc);
#pragma unroll
    for (int r2 = 0; r2 < 4; ++r2) {
      int qg = q0 + w * 16 + g * 4 + r2;
      float s0 = 0.f;
#pragma unroll
      for (int t = 0; t < 4; ++t) {
        int kg = kb * KB_ + t * 16 + c;
        float e = (kg <= qg) ? __expf(acc[t][r2]) : 0.f;
        s0 += e;
      }
#pragma unroll
      for (int m = 1; m <= 8; m <<= 1) s0 += __shfl_xor(s0, m, 64);
      rsum[r2] += s0;
    }
  }
  float invl[4];
#pragma unroll
  for (int r2 = 0; r2 < 4; ++r2) invl[r2] = 1.0f / rsum[r2];

  f32x4 oacc[8];
#pragma unroll
  for (int dt = 0; dt < 8; ++dt) oacc[dt] = zero4;

  for (int kb = 0; kb <= qb; ++kb) {
    __syncthreads();
    stageK(kb);
#pragma unroll
    for (int rr = 0; rr < 8; ++rr) {
      int d0 = 4 * (w + 4 * rr);
      const float* src = Vb + (size_t)(kb * KB_ + lane) * D_ + d0;
      float4 f = *(const float4*)src;
      float xs[4] = {f.x, f.y, f.z, f.w};
#pragma unroll
      for (int i = 0; i < 4; ++i) {
        int d = d0 + i;
        int off = d * 128 + ((lane * 2) ^ ((d & 7) << 4));
        *(unsigned short*)((char*)vts + off) = f2bf(xs[i]);
      }
    }
    __syncthreads();

    f32x4 acc[4];
    computeS(acc);

#pragma unroll
    for (int r2 = 0; r2 < 4; ++r2) {
      int qrow = g * 4 + r2;
      int qg = q0 + w * 16 + qrow;
#pragma unroll
      for (int t = 0; t < 4; ++t) {
        int kc = t * 16 + c;
        int kg = kb * KB_ + kc;
        float p = (kg <= qg) ? __expf(acc[t][r2]) * invl[r2] : 0.f;
        attnb[(size_t)qg * S_ + kg] = p;
        int off = qrow * 128 + ((kc * 2) ^ ((qrow & 7) << 4));
        *(unsigned short*)((char*)pls[w] + off) = f2bf(p);
      }
    }
    __syncthreads();

    bf16x8 pa[2];
#pragma unroll
    for (int ks = 0; ks < 2; ++ks) {
      int off = c * 128 + ((ks * 64 + g * 16) ^ ((c & 7) << 4));
      pa[ks] = *(const bf16x8*)((const char*)pls[w] + off);
    }
#pragma unroll
    for (int dt = 0; dt < 8; ++dt) {
      int d = dt * 16 + c;
      int rbase = d * 128;
      int sw = (d & 7) << 4;
#pragma unroll
      for (int ks = 0; ks < 2; ++ks) {
        int off = rbase + ((ks * 64 + g * 16) ^ sw);
        bf16x8 vf = *(const bf16x8*)((const char*)vts + off);
        oacc[dt] = __builtin_amdgcn_mfma_f32_16x16x32_bf16(pa[ks], vf, oacc[dt], 0, 0, 0);
      }
    }
  }

#pragma unroll
  for (int dt = 0; dt < 8; ++dt) {
#pragma unroll
    for (int r2 = 0; r2 < 4; ++r2) {
      int qg = q0 + w * 16 + g * 4 + r2;
      int d = dt * 16 + c;
      float qv = Qb[(size_t)qg * D_ + d];
      outb[(size_t)qg * D_ + d] = oacc[dt][r2] * qv;
    }
  }
}

extern "C" void kernel_launch(void* const* d_in, const int* in_sizes, int n_in,
                              void* d_out, int out_size, void* d_ws, size_t ws_size,
                              hipStream_t stream) {
  const float* q = (const float*)d_in[0];
  const float* k = (const float*)d_in[1];
  const float* v = (const float*)d_in[2];
  float* out  = (float*)d_out;
  float* attn = out + (size_t)BH_ * S_ * D_;

  const size_t nKV = (size_t)BH_ * S_ * D_;       // 4,194,304 elems
  const size_t need = nKV * 2 * 3;                // Khi+Klo+Vt (bf16)

  if (ws_size >= need) {
    ushort_t* Khi = (ushort_t*)d_ws;
    ushort_t* Klo = Khi + nKV;
    ushort_t* Vt  = Klo + nKV;

    convK<<<dim3((unsigned)(nKV / 8 / 256)), dim3(256), 0, stream>>>(k, Khi, Klo);
    transV<<<dim3(S_ / 64, BH_), dim3(256), 0, stream>>>(v, Vt);
    sdpa_main<<<dim3(32, BH_), dim3(256), 0, stream>>>(q, Khi, Klo, Vt, out, attn);
  } else {
    sdpa_fallback<<<dim3(S_ / QB_, BH_), dim3(256), 0, stream>>>(q, k, v, out, attn);
  }
}

// Round 5
// 179.946 us; speedup vs baseline: 1.2815x; 1.2815x over previous
//
#include <hip/hip_runtime.h>

#define BH_ 16
#define S_ 2048
#define D_ 128
#define QB_ 64
#define KB_ 64

typedef __attribute__((ext_vector_type(4))) float f32x4;
typedef __attribute__((ext_vector_type(8))) short bf16x8;
typedef unsigned short ushort_t;

__device__ __forceinline__ unsigned short f2bf(float x) {
  union { float f; unsigned int u; } v; v.f = x;
  unsigned int r = v.u + 0x7fffu + ((v.u >> 16) & 1u);  // RNE
  return (unsigned short)(r >> 16);
}
__device__ __forceinline__ float bf2f(unsigned short b) {
  union { float f; unsigned int u; } v; v.u = ((unsigned int)b) << 16;
  return v.f;
}
__device__ __forceinline__ void gload16(const void* g, void* l) {
  __builtin_amdgcn_global_load_lds(
      (const __attribute__((address_space(1))) unsigned int*)g,
      (__attribute__((address_space(3))) unsigned int*)l, 16, 0, 0);
}

// ---------- k0a: K (f32) -> Khi/Klo bf16, same [bh][s][d] layout ----------
__global__ __launch_bounds__(256) void convK(const float* __restrict__ K,
                                             ushort_t* __restrict__ hi,
                                             ushort_t* __restrict__ lo) {
  size_t i = (size_t)blockIdx.x * 256 + threadIdx.x;  // 8 floats per thread
  const float4* p = (const float4*)K + i * 2;
  float4 a = p[0], b = p[1];
  float xs[8] = {a.x, a.y, a.z, a.w, b.x, b.y, b.z, b.w};
  union { ushort_t u[8]; uint4 v; } H, L;
#pragma unroll
  for (int j = 0; j < 8; ++j) {
    unsigned short h = f2bf(xs[j]);
    H.u[j] = h;
    L.u[j] = f2bf(xs[j] - bf2f(h));
  }
  ((uint4*)hi)[i] = H.v;
  ((uint4*)lo)[i] = L.v;
}

// ---------- k0b: V (f32 [bh][s][d]) -> Vt bf16 [bh][d][s] ----------
__global__ __launch_bounds__(256) void transV(const float* __restrict__ V,
                                              ushort_t* __restrict__ Vt) {
  __shared__ ushort_t tile[64][136];
  const int tid = threadIdx.x;
  const int bh = blockIdx.y;
  const int s0 = blockIdx.x * 64;
  const float* Vb = V + ((size_t)bh * S_ + s0) * D_;
#pragma unroll
  for (int it = 0; it < 8; ++it) {
    int idx = it * 256 + tid;           // float4 index within 64x128 tile
    int fl = idx * 4;
    int s = fl >> 7, d = fl & 127;
    float4 f = *(const float4*)(Vb + (size_t)s * D_ + d);
    tile[s][d + 0] = f2bf(f.x);
    tile[s][d + 1] = f2bf(f.y);
    tile[s][d + 2] = f2bf(f.z);
    tile[s][d + 3] = f2bf(f.w);
  }
  __syncthreads();
  const int d = tid >> 1, half = tid & 1;
  union { ushort_t u[32]; uint4 v[4]; } T;
#pragma unroll
  for (int i = 0; i < 32; ++i) T.u[i] = tile[half * 32 + i][d];
  ushort_t* dst = Vt + (size_t)bh * D_ * S_ + (size_t)d * S_ + s0 + half * 32;
#pragma unroll
  for (int i = 0; i < 4; ++i) ((uint4*)dst)[i] = T.v[i];
}

// ---------- phase A: e = exp(QK^T) (unnormalized) -> attn slots; rsum ----
// Block = (pair x, k-parity, bh): tiles {31-x, x}, k-tiles == parity (mod 2).
// 512 uniform blocks (~16.5 k-tiles each). 32 KB LDS -> ~4 blocks/CU.
__global__ __launch_bounds__(256) void phaseA(
    const float* __restrict__ Q, const ushort_t* __restrict__ Khi,
    const ushort_t* __restrict__ Klo, float* __restrict__ attn,
    float* __restrict__ rsum) {
  __shared__ ushort_t khi[KB_ * D_];   // XOR-swizzled content
  __shared__ ushort_t klo[KB_ * D_];

  const int tid = threadIdx.x, w = tid >> 6, lane = tid & 63;
  const int g = lane >> 4, c = lane & 15;
  const int bh = blockIdx.y;
  const int pairIdx = (int)blockIdx.x >> 1;
  const int par = (int)blockIdx.x & 1;

  const float* Qb = Q + (size_t)bh * S_ * D_;
  const char* KhiB = (const char*)Khi + (size_t)bh * S_ * D_ * 2;
  const char* KloB = (const char*)Klo + (size_t)bh * S_ * D_ * 2;
  float* attnb = attn + (size_t)bh * S_ * S_;
  float* rsb = rsum + (size_t)bh * S_;

  auto stageK = [&](int kt) {
    const char* hs = KhiB + (size_t)kt * (KB_ * D_ * 2);
    const char* ls = KloB + (size_t)kt * (KB_ * D_ * 2);
#pragma unroll
    for (int i = 0; i < 4; ++i) {
      int ch = w * 4 + i;
      int db = ch * 1024 + lane * 16;
      int r = db >> 8, cb = db & 255;
      int so = r * 256 + (cb ^ ((r & 7) << 4));
      gload16(hs + so, (char*)khi + ch * 1024);
      gload16(ls + so, (char*)klo + ch * 1024);
    }
  };

  const f32x4 zero4 = {0.f, 0.f, 0.f, 0.f};
  bf16x8 qhi[4], qlo[4];

#pragma unroll
  for (int which = 0; which < 2; ++which) {
    const int qb = which ? pairIdx : 31 - pairIdx;
    const int q0 = qb * QB_;
    {
      const float* qrow = Qb + (size_t)(q0 + w * 16 + c) * D_;
#pragma unroll
      for (int ch = 0; ch < 4; ++ch) {
        const float* src = qrow + ch * 32 + g * 8;
        float4 a = *(const float4*)src;
        float4 b = *(const float4*)(src + 4);
        float xs[8] = {a.x, a.y, a.z, a.w, b.x, b.y, b.z, b.w};
#pragma unroll
        for (int i = 0; i < 8; ++i) {
          unsigned short h = f2bf(xs[i]);
          qhi[ch][i] = (short)h;
          qlo[ch][i] = (short)f2bf(xs[i] - bf2f(h));
        }
      }
    }
    float rs[4] = {0.f, 0.f, 0.f, 0.f};

    for (int kt = par; kt <= qb; kt += 2) {
      __syncthreads();   // all waves done reading previous K tile
      stageK(kt);
      __syncthreads();   // staged (vmcnt drained per-wave at barrier)

      f32x4 acc[4];
#pragma unroll
      for (int t = 0; t < 4; ++t) acc[t] = zero4;
#pragma unroll
      for (int c2 = 0; c2 < 4; ++c2) {
        bf16x8 kh[4], kl[4];
#pragma unroll
        for (int t = 0; t < 4; ++t) {
          int row = t * 16 + c;
          int off = row * 256 + (((c2 * 64 + g * 16)) ^ ((row & 7) << 4));
          kh[t] = *(const bf16x8*)((const char*)khi + off);
          kl[t] = *(const bf16x8*)((const char*)klo + off);
        }
#pragma unroll
        for (int t = 0; t < 4; ++t)
          acc[t] = __builtin_amdgcn_mfma_f32_16x16x32_bf16(qhi[c2], kh[t], acc[t], 0, 0, 0);
#pragma unroll
        for (int t = 0; t < 4; ++t)
          acc[t] = __builtin_amdgcn_mfma_f32_16x16x32_bf16(qlo[c2], kh[t], acc[t], 0, 0, 0);
#pragma unroll
        for (int t = 0; t < 4; ++t)
          acc[t] = __builtin_amdgcn_mfma_f32_16x16x32_bf16(qhi[c2], kl[t], acc[t], 0, 0, 0);
      }

      // e = exp(s) (0 above diag), store f32 at final attn position
#pragma unroll
      for (int r2 = 0; r2 < 4; ++r2) {
        int qg = q0 + w * 16 + g * 4 + r2;
        float* arow = attnb + (size_t)qg * S_ + kt * KB_;
#pragma unroll
        for (int t = 0; t < 4; ++t) {
          int kg = kt * KB_ + t * 16 + c;
          float e = (kg <= qg) ? __expf(acc[t][r2]) : 0.f;
          rs[r2] += e;
          arow[t * 16 + c] = e;
        }
      }
    }

    // reduce over the 16 c-lanes, one atomic per row (2 blocks/row total)
#pragma unroll
    for (int r2 = 0; r2 < 4; ++r2) {
      float s0 = rs[r2];
#pragma unroll
      for (int m = 1; m <= 8; m <<= 1) s0 += __shfl_xor(s0, m, 64);
      if (c == 0) atomicAdd(&rsb[q0 + w * 16 + g * 4 + r2], s0);
    }
  }
}

// ---------- phase B: in-place normalize + zero upper + PV + out ----------
// Block = (pair x, bh), 512 thr = 8 waves: row-group rg (0..3) x k-parity.
// V^T double-buffered per parity (64 KB LDS). e read f32 -> attn=e*inv
// (same-address RMW, load->store data dependency), e->bf16 feeds PV.
__global__ __launch_bounds__(512) void phaseB(
    const float* __restrict__ Q, const ushort_t* __restrict__ Vt,
    float* __restrict__ out, float* __restrict__ attn,
    const float* __restrict__ rsum) {
  __shared__ ushort_t vts[2][2][D_ * KB_];   // [parity][dbuf] 64 KB

  const int tid = threadIdx.x;
  const int wv = tid >> 6, rg = wv >> 1, par = wv & 1;
  const int lane = tid & 63, g = lane >> 4, c = lane & 15;
  const int bh = blockIdx.y;
  const int pairIdx = blockIdx.x;

  const float* Qb = Q + (size_t)bh * S_ * D_;
  const char* VtB = (const char*)Vt + (size_t)bh * D_ * S_ * 2;
  float* outb = out + (size_t)bh * S_ * D_;
  float* attnb = attn + (size_t)bh * S_ * S_;
  const float* rsb = rsum + (size_t)bh * S_;

  auto stageV = [&](ushort_t* dst, int kt) {
    const char* vs = VtB + (size_t)kt * (KB_ * 2);
#pragma unroll
    for (int i = 0; i < 4; ++i) {
      int ch = rg * 4 + i;
      int db = ch * 1024 + lane * 16;
      int r = db >> 7, cb = db & 127;
      int so = r * (S_ * 2) + (cb ^ ((r & 7) << 4));
      gload16(vs + so, (char*)dst + ch * 1024);
    }
  };

  const f32x4 zero4 = {0.f, 0.f, 0.f, 0.f};

#pragma unroll
  for (int which = 0; which < 2; ++which) {
    const int qb = which ? pairIdx : 31 - pairIdx;
    const int q0 = qb * QB_;
    const int n = qb + 1;
    const int iters = (n + 1) >> 1;
    const float invc = 1.0f / rsb[q0 + rg * 16 + c];

    f32x4 oacc[8];
#pragma unroll
    for (int dt = 0; dt < 8; ++dt) oacc[dt] = zero4;

    if (par < n) stageV(vts[par][0], par);
    __syncthreads();

    for (int i = 0; i < iters; ++i) {
      const int kt = 2 * i + par;
      const int cur = i & 1;
      const int nxt = kt + 2;
      if (nxt < n) stageV(vts[par][cur ^ 1], nxt);

      if (kt < n) {
        float* arow = attnb + (size_t)(q0 + rg * 16 + c) * S_ + kt * KB_;
        bf16x8 pa[2];
#pragma unroll
        for (int ks = 0; ks < 2; ++ks) {
          float* ep = arow + ks * 32 + g * 8;
          float4 ea = *(const float4*)ep;
          float4 eb = *(const float4*)(ep + 4);
          float xs[8] = {ea.x, ea.y, ea.z, ea.w, eb.x, eb.y, eb.z, eb.w};
#pragma unroll
          for (int ii = 0; ii < 8; ++ii) pa[ks][ii] = (short)f2bf(xs[ii]);
          float4 sa = make_float4(ea.x * invc, ea.y * invc, ea.z * invc, ea.w * invc);
          float4 sb = make_float4(eb.x * invc, eb.y * invc, eb.z * invc, eb.w * invc);
          *(float4*)ep = sa;          // in-place, depends on the load -> ordered
          *(float4*)(ep + 4) = sb;
        }
#pragma unroll
        for (int ks = 0; ks < 2; ++ks) {
#pragma unroll
          for (int dt = 0; dt < 8; ++dt) {
            int d = dt * 16 + c;
            int off = d * 128 + ((ks * 64 + g * 16) ^ ((d & 7) << 4));
            bf16x8 vf = *(const bf16x8*)((const char*)vts[par][cur] + off);
            oacc[dt] = __builtin_amdgcn_mfma_f32_16x16x32_bf16(pa[ks], vf, oacc[dt], 0, 0, 0);
          }
        }
      }
      __syncthreads();
    }

    // combine parity halves of O via LDS (reuse vts space), write out
    char* comb = (char*)vts;
    if (par == 1) {
      char* base = comb + (size_t)rg * 9216 + lane * 144;
#pragma unroll
      for (int dt = 0; dt < 8; ++dt) *(f32x4*)(base + dt * 16) = oacc[dt];
    }
    __syncthreads();
    if (par == 0) {
      const char* base = comb + (size_t)rg * 9216 + lane * 144;
      float invr[4];
#pragma unroll
      for (int r2 = 0; r2 < 4; ++r2) invr[r2] = 1.0f / rsb[q0 + rg * 16 + g * 4 + r2];
#pragma unroll
      for (int dt = 0; dt < 8; ++dt) {
        f32x4 o1 = *(const f32x4*)(base + dt * 16);
        int d = dt * 16 + c;
#pragma unroll
        for (int r2 = 0; r2 < 4; ++r2) {
          int qg = q0 + rg * 16 + g * 4 + r2;
          outb[(size_t)qg * D_ + d] =
              (oacc[dt][r2] + o1[r2]) * invr[r2] * Qb[(size_t)qg * D_ + d];
        }
      }
    }
    // zero upper triangle cols [64n, 2048) for this tile's 64 rows
    {
      int r = tid >> 3;
      float* rowp = attnb + (size_t)(q0 + r) * S_;
      for (int col = n * KB_ + (tid & 7) * 4; col < S_; col += 32)
        *(float4*)(rowp + col) = make_float4(0.f, 0.f, 0.f, 0.f);
    }
    __syncthreads();  // combine reads done before next tile's staging
  }
}

// ---------- fallback (round-1 kernel, self-contained) ----------
__global__ __launch_bounds__(256, 2)
void sdpa_fallback(const float* __restrict__ Q, const float* __restrict__ K,
                   const float* __restrict__ V, float* __restrict__ out,
                   float* __restrict__ attn)
{
  __shared__ unsigned short khi[KB_ * D_];
  __shared__ unsigned short klo[KB_ * D_];
  __shared__ unsigned short vts[D_ * KB_];
  __shared__ unsigned short pls[4][16 * KB_];

  const int tid  = threadIdx.x;
  const int w    = tid >> 6;
  const int lane = tid & 63;
  const int g    = lane >> 4;
  const int c    = lane & 15;

  const int bh = blockIdx.y;
  const int qb = (int)gridDim.x - 1 - (int)blockIdx.x;
  const int q0 = qb * QB_;

  const float* Qb = Q + (size_t)bh * S_ * D_;
  const float* Kb = K + (size_t)bh * S_ * D_;
  const float* Vb = V + (size_t)bh * S_ * D_;
  float* outb  = out  + (size_t)bh * S_ * D_;
  float* attnb = attn + (size_t)bh * S_ * S_;

  {
    const int colstart = q0 + QB_;
    for (int r = 0; r < QB_; ++r) {
      float* rowp = attnb + (size_t)(q0 + r) * S_;
      for (int col = colstart + tid * 4; col < S_; col += 1024)
        *(float4*)(rowp + col) = make_float4(0.f, 0.f, 0.f, 0.f);
    }
  }

  bf16x8 qhi[4], qlo[4];
  {
    const float* qrow = Qb + (size_t)(q0 + w * 16 + c) * D_;
#pragma unroll
    for (int ch = 0; ch < 4; ++ch) {
      const float* src = qrow + ch * 32 + g * 8;
      float4 a = *(const float4*)src;
      float4 b = *(const float4*)(src + 4);
      float xs[8] = {a.x, a.y, a.z, a.w, b.x, b.y, b.z, b.w};
#pragma unroll
      for (int i = 0; i < 8; ++i) {
        unsigned short h = f2bf(xs[i]);
        unsigned short l = f2bf(xs[i] - bf2f(h));
        qhi[ch][i] = (short)h;
        qlo[ch][i] = (short)l;
      }
    }
  }

  auto stageK = [&](int kb) {
#pragma unroll
    for (int rr = 0; rr < 8; ++rr) {
      int flat = tid * 4 + rr * 1024;
      int kj = flat >> 7, d0 = flat & 127;
      const float* src = Kb + (size_t)(kb * KB_ + kj) * D_ + d0;
      float4 f = *(const float4*)src;
      unsigned short h0 = f2bf(f.x), h1 = f2bf(f.y), h2 = f2bf(f.z), h3 = f2bf(f.w);
      unsigned short l0 = f2bf(f.x - bf2f(h0)), l1 = f2bf(f.y - bf2f(h1));
      unsigned short l2 = f2bf(f.z - bf2f(h2)), l3 = f2bf(f.w - bf2f(h3));
      int off = kj * 256 + ((d0 * 2) ^ ((kj & 7) << 4));
      *(uint2*)((char*)khi + off) =
          make_uint2((unsigned)h0 | ((unsigned)h1 << 16), (unsigned)h2 | ((unsigned)h3 << 16));
      *(uint2*)((char*)klo + off) =
          make_uint2((unsigned)l0 | ((unsigned)l1 << 16), (unsigned)l2 | ((unsigned)l3 << 16));
    }
  };

  const f32x4 zero4 = {0.f, 0.f, 0.f, 0.f};
  auto computeS = [&](f32x4* acc) {
#pragma unroll
    for (int t = 0; t < 4; ++t) {
      acc[t] = zero4;
      int row = t * 16 + c;
      int rbase = row * 256;
      int sw = (row & 7) << 4;
#pragma unroll
      for (int c2 = 0; c2 < 4; ++c2) {
        int off = rbase + ((c2 * 64 + g * 16) ^ sw);
        bf16x8 kh_ = *(const bf16x8*)((const char*)khi + off);
        bf16x8 kl_ = *(const bf16x8*)((const char*)klo + off);
        acc[t] = __builtin_amdgcn_mfma_f32_16x16x32_bf16(qhi[c2], kh_, acc[t], 0, 0, 0);
        acc[t] = __builtin_amdgcn_mfma_f32_16x16x32_bf16(qhi[c2], kl_, acc[t], 0, 0, 0);
        acc[t] = __builtin_amdgcn_mfma_f32_16x16x32_bf16(qlo[c2], kh_, acc[t], 0, 0, 0);
      }
    }
  };

  float rsum[4] = {0.f, 0.f, 0.f, 0.f};
  for (int kb = 0; kb <= qb; ++kb) {
    __syncthreads();
    stageK(kb);
    __syncthreads();
    f32x4 acc[4];
    computeS(acc);
#pragma unroll
    for (int r2 = 0; r2 < 4; ++r2) {
      int qg = q0 + w * 16 + g * 4 + r2;
      float s0 = 0.f;
#pragma unroll
      for (int t = 0; t < 4; ++t) {
        int kg = kb * KB_ + t * 16 + c;
        float e = (kg <= qg) ? __expf(acc[t][r2]) : 0.f;
        s0 += e;
      }
#pragma unroll
      for (int m = 1; m <= 8; m <<= 1) s0 += __shfl_xor(s0, m, 64);
      rsum[r2] += s0;
    }
  }
  float invl[4];
#pragma unroll
  for (int r2 = 0; r2 < 4; ++r2) invl[r2] = 1.0f / rsum[r2];

  f32x4 oacc[8];
#pragma unroll
  for (int dt = 0; dt < 8; ++dt) oacc[dt] = zero4;

  for (int kb = 0; kb <= qb; ++kb) {
    __syncthreads();
    stageK(kb);
#pragma unroll
    for (int rr = 0; rr < 8; ++rr) {
      int d0 = 4 * (w + 4 * rr);
      const float* src = Vb + (size_t)(kb * KB_ + lane) * D_ + d0;
      float4 f = *(const float4*)src;
      float xs[4] = {f.x, f.y, f.z, f.w};
#pragma unroll
      for (int i = 0; i < 4; ++i) {
        int d = d0 + i;
        int off = d * 128 + ((lane * 2) ^ ((d & 7) << 4));
        *(unsigned short*)((char*)vts + off) = f2bf(xs[i]);
      }
    }
    __syncthreads();

    f32x4 acc[4];
    computeS(acc);

#pragma unroll
    for (int r2 = 0; r2 < 4; ++r2) {
      int qrow = g * 4 + r2;
      int qg = q0 + w * 16 + qrow;
#pragma unroll
      for (int t = 0; t < 4; ++t) {
        int kc = t * 16 + c;
        int kg = kb * KB_ + kc;
        float p = (kg <= qg) ? __expf(acc[t][r2]) * invl[r2] : 0.f;
        attnb[(size_t)qg * S_ + kg] = p;
        int off = qrow * 128 + ((kc * 2) ^ ((qrow & 7) << 4));
        *(unsigned short*)((char*)pls[w] + off) = f2bf(p);
      }
    }
    __syncthreads();

    bf16x8 pa[2];
#pragma unroll
    for (int ks = 0; ks < 2; ++ks) {
      int off = c * 128 + ((ks * 64 + g * 16) ^ ((c & 7) << 4));
      pa[ks] = *(const bf16x8*)((const char*)pls[w] + off);
    }
#pragma unroll
    for (int dt = 0; dt < 8; ++dt) {
      int d = dt * 16 + c;
      int rbase = d * 128;
      int sw = (d & 7) << 4;
#pragma unroll
      for (int ks = 0; ks < 2; ++ks) {
        int off = rbase + ((ks * 64 + g * 16) ^ sw);
        bf16x8 vf = *(const bf16x8*)((const char*)vts + off);
        oacc[dt] = __builtin_amdgcn_mfma_f32_16x16x32_bf16(pa[ks], vf, oacc[dt], 0, 0, 0);
      }
    }
  }

#pragma unroll
  for (int dt = 0; dt < 8; ++dt) {
#pragma unroll
    for (int r2 = 0; r2 < 4; ++r2) {
      int qg = q0 + w * 16 + g * 4 + r2;
      int d = dt * 16 + c;
      float qv = Qb[(size_t)qg * D_ + d];
      outb[(size_t)qg * D_ + d] = oacc[dt][r2] * qv;
    }
  }
}

extern "C" void kernel_launch(void* const* d_in, const int* in_sizes, int n_in,
                              void* d_out, int out_size, void* d_ws, size_t ws_size,
                              hipStream_t stream) {
  const float* q = (const float*)d_in[0];
  const float* k = (const float*)d_in[1];
  const float* v = (const float*)d_in[2];
  float* out  = (float*)d_out;
  float* attn = out + (size_t)BH_ * S_ * D_;

  const size_t nKV = (size_t)BH_ * S_ * D_;                 // 4,194,304
  const size_t need = nKV * 2 * 3 + (size_t)BH_ * S_ * 4;   // Khi+Klo+Vt+rsum

  if (ws_size >= need) {
    ushort_t* Khi = (ushort_t*)d_ws;
    ushort_t* Klo = Khi + nKV;
    ushort_t* Vt  = Klo + nKV;
    float* rsumW  = (float*)(Vt + nKV);

    convK<<<dim3((unsigned)(nKV / 8 / 256)), dim3(256), 0, stream>>>(k, Khi, Klo);
    transV<<<dim3(S_ / 64, BH_), dim3(256), 0, stream>>>(v, Vt);
    hipMemsetAsync(rsumW, 0, (size_t)BH_ * S_ * 4, stream);
    phaseA<<<dim3(32, BH_), dim3(256), 0, stream>>>(q, Khi, Klo, attn, rsumW);
    phaseB<<<dim3(16, BH_), dim3(512), 0, stream>>>(q, Vt, out, attn, rsumW);
  } else {
    sdpa_fallback<<<dim3(S_ / QB_, BH_), dim3(256), 0, stream>>>(q, k, v, out, attn);
  }
}